// Round 16
// baseline (73.064 us; speedup 1.0000x reference)
//
#include <hip/hip_runtime.h>
#include <math.h>

#define LOG2E  1.4426950408889634f
#define LN2    0.6931471805599453f

// Problem constants (fixed by setup_inputs)
#define T_DIM 1024
#define B_DIM 128
#define C_DIM 256
#define S_DIM 64
#define L_DIM (2 * S_DIM + 1)  // 129
#define CH 16                  // timesteps per chunk
#define NCH (T_DIM / CH)       // 64 chunks
#define RBUF 4                 // raw-row ring (producer-private)
#define PBUF 6                 // converted-pair ring (cross-wave)

__device__ __forceinline__ float fexp2(float x) { return __builtin_amdgcn_exp2f(x); }
__device__ __forceinline__ float flog2(float x) { return __builtin_amdgcn_logf(x); }

// lane i <- lane i-1; lane 0 <- 0. wave_shr:1 DPP (gfx9 ctrl 0x138).
__device__ __forceinline__ int dpp_shr1_i(int x) {
    return __builtin_amdgcn_update_dpp(0, x, 0x138 /*WAVE_SHR1*/, 0xF, 0xF, false);
}

// Async global->LDS, 16B per lane (per-lane src, wave-uniform dest).
#define GLOAD_LDS16(gp, lp)                                                    \
    __builtin_amdgcn_global_load_lds(                                          \
        (const __attribute__((address_space(1))) void*)(gp),                   \
        (__attribute__((address_space(3))) void*)(lp), 16, 0, 0)

#define VMWAIT(N_) asm volatile("s_waitcnt vmcnt(" #N_ ")" ::: "memory")
#define LGKM0()    asm volatile("s_waitcnt lgkmcnt(0)" ::: "memory")

// PRODUCER/CONSUMER, LDS-flag handshake, no per-chunk barriers.
// Producer (wave 1): stage rows -> vmcnt wait -> divergent e1-gather ->
// exp2 convert -> write packed float2{plv,pbv} to pcv ring -> publish flag.
// Consumer (wave 0): poll flag -> 16 contiguous ds_read_b64 -> 16 pure-VALU
// recursion steps (no transcendentals, no divergent LDS, no VMEM).
// Alpha: LINEAR domain, per-lane exponent el (true_alpha = a * 2^el).
__global__ __launch_bounds__(128) void ctc_alpha_kernel(
    const float* __restrict__ log_probs,    // (T, B, C)
    const int* __restrict__ targets,        // (B, S)
    const int* __restrict__ target_lengths, // (B,)
    float* __restrict__ per_batch)          // (B,) loss_b / len_b
{
    const int b = blockIdx.x;
    const int tid = threadIdx.x;
    const int lane = tid & 63;
    const int wid = tid >> 6;   // 0 = consumer, 1 = producer

    __shared__ float  rbuf[RBUF][CH][C_DIM];   // 64 KB raw class rows
    __shared__ float2 pcv[PBUF][CH][64];       // 48 KB converted {plv,pbv}
    __shared__ int prodf;  // # chunks converted & published
    __shared__ int consf;  // # chunks consumed

    const int e1 = targets[b * S_DIM + lane];               // class of state 2l+1
    const int ep = (lane > 0) ? targets[b * S_DIM + lane - 1] : 0;
    const bool skip = (lane > 0) && (e1 != ep);

    const float* base = log_probs + (size_t)b * C_DIM;
    const size_t stride = (size_t)B_DIM * C_DIM;  // floats per timestep

    // t = 0 init (linear domain, scale el=0) — consumer state.
    float i0 = base[0];
    float ie = base[e1];
    float a0 = (lane == 0) ? fexp2(i0 * LOG2E) : 0.0f;  // alpha[0]
    float a1 = (lane == 0) ? fexp2(ie * LOG2E) : 0.0f;  // alpha[1]
    float a2 = 0.0f;                                    // alpha[128]
    int el = 0;    // per-lane: log2(true alpha) = log2(a) + el
    int dexp = 0;  // eprev - el within a 4-step rescale window

    if (tid == 0) { prodf = 0; consf = 0; }
    __syncthreads();  // the only barrier in the kernel

#define RESCALE()                                                              \
    do {                                                                       \
        float mx_ = fmaxf(a0, fmaxf(a1, a2));                                  \
        int eb_ = (int)((__float_as_uint(mx_) >> 23) & 0xFFu) - 127;           \
        el += eb_;                                                             \
        float sc_ = __uint_as_float((unsigned)(127 - eb_) << 23);              \
        a0 *= sc_; a1 *= sc_; a2 *= sc_;                                       \
    } while (0)

#define ISSUE_CHUNK(C_, RB_)                                                   \
    do {                                                                       \
        const int t0_ = 1 + CH * (C_);                                         \
        _Pragma("unroll")                                                      \
        for (int k_ = 0; k_ < CH; ++k_) {                                      \
            int t_ = t0_ + k_;                                                 \
            t_ = (t_ < T_DIM) ? t_ : (T_DIM - 1);                              \
            GLOAD_LDS16(base + (size_t)t_ * stride + 4 * lane,                 \
                        &rbuf[RB_][k_][0]);                                    \
        }                                                                      \
    } while (0)

    // Producer: gather chunk's label/blank values, convert, write pairs.
#define CONVERT_CHUNK(RB_, PB_)                                                \
    do {                                                                       \
        _Pragma("unroll")                                                      \
        for (int k_ = 0; k_ < CH; ++k_) {                                      \
            float pl_ = rbuf[RB_][k_][e1];                                     \
            float pb_ = rbuf[RB_][k_][0];                                      \
            float2 v_;                                                         \
            v_.x = fexp2(pl_ * LOG2E);                                         \
            v_.y = fexp2(pb_ * LOG2E);                                         \
            pcv[PB_][k_][lane] = v_;                                           \
        }                                                                      \
    } while (0)

    // Activation-phase step (first 9 chunks): full virgin-adopt logic.
#define ACT_STEP(PBV, PLV, K_)                                                 \
    do {                                                                       \
        float am1_ = __int_as_float(dpp_shr1_i(__float_as_int(a1)));           \
        int eprev_ = dpp_shr1_i(el);                                           \
        int iz_ = __float_as_int(a0) | __float_as_int(a1) |                    \
                  __float_as_int(a2);                                          \
        int ele_ = (iz_ == 0) ? eprev_ : el;                                   \
        float am1s_ = ldexpf(am1_, eprev_ - ele_);                             \
        el = ele_;                                                             \
        float n0_ = (a0 + am1s_) * (PBV);                                      \
        float s2_ = skip ? am1s_ : 0.0f;                                       \
        float n1_ = (a1 + a0 + s2_) * (PLV);                                   \
        float n2_ = (a2 + a1) * (PBV);                                         \
        a0 = n0_; a1 = n1_; a2 = n2_;                                          \
        if (((K_) & 3) == 3) RESCALE();                                        \
    } while (0)

    // Steady-state step: dexp reused within the 4-step window.
#define STREAM_STEP(PBV, PLV)                                                  \
    do {                                                                       \
        float am1_ = __int_as_float(dpp_shr1_i(__float_as_int(a1)));           \
        float am1s_ = ldexpf(am1_, dexp);                                      \
        float n0_ = (a0 + am1s_) * (PBV);                                      \
        float s2_ = skip ? am1s_ : 0.0f;                                       \
        float n1_ = (a1 + a0 + s2_) * (PLV);                                   \
        float n2_ = (a2 + a1) * (PBV);                                         \
        a0 = n0_; a1 = n1_; a2 = n2_;                                          \
    } while (0)

#define GATHER_PCV(PB_)                                                        \
    float2 pvr_[CH];                                                           \
    _Pragma("unroll")                                                          \
    for (int k_ = 0; k_ < CH; ++k_) {                                          \
        pvr_[k_] = pcv[PB_][k_][lane];                                         \
    }                                                                          \
    __builtin_amdgcn_sched_barrier(0)

#define ACT_CHUNK(PB_)                                                         \
    do {                                                                       \
        GATHER_PCV(PB_);                                                       \
        _Pragma("unroll")                                                      \
        for (int k_ = 0; k_ < CH; ++k_) {                                      \
            ACT_STEP(pvr_[k_].y, pvr_[k_].x, k_);                              \
        }                                                                      \
    } while (0)

#define STREAM_CHUNK(PB_)                                                      \
    do {                                                                       \
        GATHER_PCV(PB_);                                                       \
        _Pragma("unroll")                                                      \
        for (int q_ = 0; q_ < 4; ++q_) {                                       \
            dexp = dpp_shr1_i(el) - el;                                        \
            STREAM_STEP(pvr_[4 * q_ + 0].y, pvr_[4 * q_ + 0].x);               \
            STREAM_STEP(pvr_[4 * q_ + 1].y, pvr_[4 * q_ + 1].x);               \
            STREAM_STEP(pvr_[4 * q_ + 2].y, pvr_[4 * q_ + 2].x);               \
            STREAM_STEP(pvr_[4 * q_ + 3].y, pvr_[4 * q_ + 3].x);               \
            RESCALE();                                                         \
        }                                                                      \
    } while (0)

#define TAIL_CHUNK(PB_)                                                        \
    do {                                                                       \
        GATHER_PCV(PB_);                                                       \
        _Pragma("unroll")                                                      \
        for (int q_ = 0; q_ < 3; ++q_) {                                       \
            dexp = dpp_shr1_i(el) - el;                                        \
            STREAM_STEP(pvr_[4 * q_ + 0].y, pvr_[4 * q_ + 0].x);               \
            STREAM_STEP(pvr_[4 * q_ + 1].y, pvr_[4 * q_ + 1].x);               \
            STREAM_STEP(pvr_[4 * q_ + 2].y, pvr_[4 * q_ + 2].x);               \
            STREAM_STEP(pvr_[4 * q_ + 3].y, pvr_[4 * q_ + 3].x);               \
            RESCALE();                                                         \
        }                                                                      \
        dexp = dpp_shr1_i(el) - el;                                            \
        STREAM_STEP(pvr_[12].y, pvr_[12].x);                                   \
        STREAM_STEP(pvr_[13].y, pvr_[13].x);                                   \
        STREAM_STEP(pvr_[14].y, pvr_[14].x);                                   \
    } while (0)

    if (wid == 1) {
        // PRODUCER: stage + gather + convert + publish.
        volatile int* pf = &prodf;
        volatile int* cf = &consf;
        ISSUE_CHUNK(0, 0);
        ISSUE_CHUNK(1, 1);
        for (int c = 2; c < NCH; ++c) {
            // pcv[(c-2)%PBUF] reuse: chunk c-2-PBUF must be consumed.
            if (c >= PBUF + 2) {
                while (*cf < c - PBUF - 1) __builtin_amdgcn_s_sleep(1);
            }
            ISSUE_CHUNK(c, c & (RBUF - 1));
            VMWAIT(32);  // chunks <= c-2 have fully landed in rbuf
            __builtin_amdgcn_sched_barrier(0);
            CONVERT_CHUNK((c - 2) & (RBUF - 1), (c - 2) % PBUF);
            LGKM0();  // pair writes visible before flag
            if (lane == 0) *pf = c - 1;
        }
        VMWAIT(16);
        __builtin_amdgcn_sched_barrier(0);
        CONVERT_CHUNK((NCH - 2) & (RBUF - 1), (NCH - 2) % PBUF);
        LGKM0();
        if (lane == 0) *pf = NCH - 1;
        VMWAIT(0);
        __builtin_amdgcn_sched_barrier(0);
        CONVERT_CHUNK((NCH - 1) & (RBUF - 1), (NCH - 1) % PBUF);
        LGKM0();
        if (lane == 0) *pf = NCH;
    } else {
        // CONSUMER: zero VMEM, zero transcendentals, zero barriers.
        volatile int* pf = &prodf;
        volatile int* cf = &consf;
        for (int c = 0; c < NCH; ++c) {
            while (*pf < c + 1) { /* producer normally ahead */ }
            __builtin_amdgcn_sched_barrier(0);
            asm volatile("" ::: "memory");  // pin data reads after flag read
            if (c < 9)            ACT_CHUNK(c % PBUF);
            else if (c < NCH - 1) STREAM_CHUNK(c % PBUF);
            else                  TAIL_CHUNK(c % PBUF);
            if (lane == 0) *cf = c + 1;
        }
    }

#undef TAIL_CHUNK
#undef STREAM_CHUNK
#undef ACT_CHUNK
#undef GATHER_PCV
#undef STREAM_STEP
#undef ACT_STEP
#undef CONVERT_CHUNK
#undef ISSUE_CHUNK
#undef RESCALE

    // Terminal (consumer wave): states 2*len and 2*len-1 via uniform shuffles.
    if (wid == 0) {
        const int len = target_lengths[b];
        float la0 = flog2(a0) + (float)el;
        float la1 = flog2(a1) + (float)el;
        float la2 = flog2(a2) + (float)el;
        float x = (len == S_DIM) ? __shfl(la2, 63, 64) : __shfl(la0, len, 64);
        float y = __shfl(la1, len - 1, 64);
        if (lane == 0) {
            float mx = fmaxf(x, y);
            float lse2 = mx + flog2(1.0f + fexp2(-fabsf(x - y)));
            float loss = -(lse2 * LN2);
            if (!isfinite(loss) || !(loss < 1e29f)) loss = 0.0f;
            per_batch[b] = loss / (float)len;
        }
    }
}

// Single-wave deterministic reduction: mean over B of per_batch.
__global__ __launch_bounds__(64) void ctc_reduce_kernel(
    const float* __restrict__ per_batch, float* __restrict__ out)
{
    const int lane = threadIdx.x;
    float v = per_batch[lane] + per_batch[lane + 64];
    #pragma unroll
    for (int off = 32; off > 0; off >>= 1) {
        v += __shfl_down(v, off, 64);
    }
    if (lane == 0) out[0] = v / (float)B_DIM;
}

extern "C" void kernel_launch(void* const* d_in, const int* in_sizes, int n_in,
                              void* d_out, int out_size, void* d_ws, size_t ws_size,
                              hipStream_t stream) {
    const float* log_probs = (const float*)d_in[0];
    const int* targets = (const int*)d_in[1];
    const int* target_lengths = (const int*)d_in[2];
    float* out = (float*)d_out;
    float* per_batch = (float*)d_ws;  // B_DIM floats of scratch

    ctc_alpha_kernel<<<B_DIM, 128, 0, stream>>>(log_probs, targets,
                                                target_lengths, per_batch);
    ctc_reduce_kernel<<<1, 64, 0, stream>>>(per_batch, out);
}

// Round 17
// 51.764 us; speedup vs baseline: 1.4115x; 1.4115x over previous
//
#include <hip/hip_runtime.h>
#include <math.h>

#define LOG2E  1.4426950408889634f
#define LN2    0.6931471805599453f

// Problem constants (fixed by setup_inputs)
#define T_DIM 1024
#define B_DIM 128
#define C_DIM 256
#define S_DIM 64
#define L_DIM (2 * S_DIM + 1)  // 129
#define CH 16                  // timesteps per LDS-staged chunk
#define NCH (T_DIM / CH)       // 64 chunks
#define NBUF 6                 // LDS buffer ring depth (96 KB)

__device__ __forceinline__ float fexp2(float x) { return __builtin_amdgcn_exp2f(x); }
__device__ __forceinline__ float flog2(float x) { return __builtin_amdgcn_logf(x); }

// lane i <- lane i-1; lane 0 <- 0. wave_shr:1 DPP (gfx9 ctrl 0x138).
__device__ __forceinline__ int dpp_shr1_i(int x) {
    return __builtin_amdgcn_update_dpp(0, x, 0x138 /*WAVE_SHR1*/, 0xF, 0xF, false);
}

// Async global->LDS, 16B per lane (per-lane src, wave-uniform dest).
#define GLOAD_LDS16(gp, lp)                                                    \
    __builtin_amdgcn_global_load_lds(                                          \
        (const __attribute__((address_space(1))) void*)(gp),                   \
        (__attribute__((address_space(3))) void*)(lp), 16, 0, 0)

#define VMWAIT(N_) asm volatile("s_waitcnt vmcnt(" #N_ ")" ::: "memory")

// PRODUCER/CONSUMER with LDS-flag handshake (R15 structure) plus
// consumer-side register double-buffer: while computing chunk c from
// register set X, the poll + 32 divergent ds_reads for chunk c+1 land in
// register set Y — gather latency fully hidden under compute.
// Alpha: LINEAR domain, per-lane exponent el (true_alpha = a * 2^el).
__global__ __launch_bounds__(128) void ctc_alpha_kernel(
    const float* __restrict__ log_probs,    // (T, B, C)
    const int* __restrict__ targets,        // (B, S)
    const int* __restrict__ target_lengths, // (B,)
    float* __restrict__ per_batch)          // (B,) loss_b / len_b
{
    const int b = blockIdx.x;
    const int tid = threadIdx.x;
    const int lane = tid & 63;
    const int wid = tid >> 6;   // 0 = consumer, 1 = producer

    __shared__ float rbuf[NBUF][CH][C_DIM];  // 96 KB staged class rows
    __shared__ int prodf;  // # chunks fully landed in LDS
    __shared__ int consf;  // # chunks fully consumed

    const int e1 = targets[b * S_DIM + lane];               // class of state 2l+1
    const int ep = (lane > 0) ? targets[b * S_DIM + lane - 1] : 0;
    const bool skip = (lane > 0) && (e1 != ep);

    const float* base = log_probs + (size_t)b * C_DIM;
    const size_t stride = (size_t)B_DIM * C_DIM;  // floats per timestep

    // t = 0 init (linear domain, scale el=0) — consumer wave state.
    float i0 = base[0];
    float ie = base[e1];
    float a0 = (lane == 0) ? fexp2(i0 * LOG2E) : 0.0f;  // alpha[0]
    float a1 = (lane == 0) ? fexp2(ie * LOG2E) : 0.0f;  // alpha[1]
    float a2 = 0.0f;                                    // alpha[128]
    int el = 0;    // per-lane: log2(true alpha) = log2(a) + el
    int dexp = 0;  // eprev - el within a 4-step rescale window

    if (tid == 0) { prodf = 0; consf = 0; }
    __syncthreads();  // the only barrier in the kernel

#define RESCALE()                                                              \
    do {                                                                       \
        float mx_ = fmaxf(a0, fmaxf(a1, a2));                                  \
        int eb_ = (int)((__float_as_uint(mx_) >> 23) & 0xFFu) - 127;           \
        el += eb_;                                                             \
        float sc_ = __uint_as_float((unsigned)(127 - eb_) << 23);              \
        a0 *= sc_; a1 *= sc_; a2 *= sc_;                                       \
    } while (0)

#define ISSUE_CHUNK(C_, BUF_)                                                  \
    do {                                                                       \
        const int t0_ = 1 + CH * (C_);                                         \
        _Pragma("unroll")                                                      \
        for (int k_ = 0; k_ < CH; ++k_) {                                      \
            int t_ = t0_ + k_;                                                 \
            t_ = (t_ < T_DIM) ? t_ : (T_DIM - 1);                              \
            GLOAD_LDS16(base + (size_t)t_ * stride + 4 * lane,                 \
                        &rbuf[BUF_][k_][0]);                                   \
        }                                                                      \
    } while (0)

    // Activation-phase step (chunks 0..9): full virgin-adopt logic.
#define ACT_STEP(LPB, LPL, K_)                                                 \
    do {                                                                       \
        float pbv_ = fexp2((LPB) * LOG2E);                                     \
        float plv_ = fexp2((LPL) * LOG2E);                                     \
        float am1_ = __int_as_float(dpp_shr1_i(__float_as_int(a1)));           \
        int eprev_ = dpp_shr1_i(el);                                           \
        int iz_ = __float_as_int(a0) | __float_as_int(a1) |                    \
                  __float_as_int(a2);                                          \
        int ele_ = (iz_ == 0) ? eprev_ : el;                                   \
        float am1s_ = ldexpf(am1_, eprev_ - ele_);                             \
        el = ele_;                                                             \
        float n0_ = (a0 + am1s_) * pbv_;                                       \
        float s2_ = skip ? am1s_ : 0.0f;                                       \
        float n1_ = (a1 + a0 + s2_) * plv_;                                    \
        float n2_ = (a2 + a1) * pbv_;                                          \
        a0 = n0_; a1 = n1_; a2 = n2_;                                          \
        if (((K_) & 3) == 3) RESCALE();                                        \
    } while (0)

    // Steady-state step: el/eprev constant within the window -> dexp reused.
#define STREAM_STEP(LPB, LPL)                                                  \
    do {                                                                       \
        float pbv_ = fexp2((LPB) * LOG2E);                                     \
        float plv_ = fexp2((LPL) * LOG2E);                                     \
        float am1_ = __int_as_float(dpp_shr1_i(__float_as_int(a1)));           \
        float am1s_ = ldexpf(am1_, dexp);                                      \
        float n0_ = (a0 + am1s_) * pbv_;                                       \
        float s2_ = skip ? am1s_ : 0.0f;                                       \
        float n1_ = (a1 + a0 + s2_) * plv_;                                    \
        float n2_ = (a2 + a1) * pbv_;                                          \
        a0 = n0_; a1 = n1_; a2 = n2_;                                          \
    } while (0)

    // Poll producer flag to >= N_, then fence so later rbuf reads stay after.
#define POLL(N_)                                                               \
    do {                                                                       \
        while (*pf < (N_)) { }                                                 \
        __builtin_amdgcn_sched_barrier(0);                                     \
        asm volatile("" ::: "memory");                                         \
    } while (0)

    // Issue chunk's 32 divergent gathers into a NAMED register set.
#define GATHER_TO(PLX, PBX, BUF_)                                              \
    do {                                                                       \
        _Pragma("unroll")                                                      \
        for (int k_ = 0; k_ < CH; ++k_) {                                      \
            PLX[k_] = rbuf[BUF_][k_][e1];                                      \
            PBX[k_] = rbuf[BUF_][k_][0];                                       \
        }                                                                      \
    } while (0)

#define ACT_FROM(PLX, PBX)                                                     \
    do {                                                                       \
        _Pragma("unroll")                                                      \
        for (int k_ = 0; k_ < CH; ++k_) {                                      \
            ACT_STEP(PBX[k_], PLX[k_], k_);                                    \
        }                                                                      \
    } while (0)

#define STREAM_FROM(PLX, PBX)                                                  \
    do {                                                                       \
        _Pragma("unroll")                                                      \
        for (int q_ = 0; q_ < 4; ++q_) {                                       \
            dexp = dpp_shr1_i(el) - el;                                        \
            STREAM_STEP(PBX[4 * q_ + 0], PLX[4 * q_ + 0]);                     \
            STREAM_STEP(PBX[4 * q_ + 1], PLX[4 * q_ + 1]);                     \
            STREAM_STEP(PBX[4 * q_ + 2], PLX[4 * q_ + 2]);                     \
            STREAM_STEP(PBX[4 * q_ + 3], PLX[4 * q_ + 3]);                     \
            RESCALE();                                                         \
        }                                                                      \
    } while (0)

#define TAIL_FROM(PLX, PBX)                                                    \
    do {                                                                       \
        _Pragma("unroll")                                                      \
        for (int q_ = 0; q_ < 3; ++q_) {                                       \
            dexp = dpp_shr1_i(el) - el;                                        \
            STREAM_STEP(PBX[4 * q_ + 0], PLX[4 * q_ + 0]);                     \
            STREAM_STEP(PBX[4 * q_ + 1], PLX[4 * q_ + 1]);                     \
            STREAM_STEP(PBX[4 * q_ + 2], PLX[4 * q_ + 2]);                     \
            STREAM_STEP(PBX[4 * q_ + 3], PLX[4 * q_ + 3]);                     \
            RESCALE();                                                         \
        }                                                                      \
        dexp = dpp_shr1_i(el) - el;                                            \
        STREAM_STEP(PBX[12], PLX[12]);                                         \
        STREAM_STEP(PBX[13], PLX[13]);                                         \
        STREAM_STEP(PBX[14], PLX[14]);                                         \
    } while (0)

    if (wid == 1) {
        // PRODUCER: free-running stager (identical to R15).
        volatile int* pf = &prodf;
        volatile int* cf = &consf;
        for (int c = 0; c < NCH; ++c) {
            if (c >= NBUF) {
                while (*cf < c - NBUF + 1) __builtin_amdgcn_s_sleep(1);
            }
            ISSUE_CHUNK(c, c % NBUF);
            VMWAIT(32);  // chunks <= c-2 have fully landed
            __builtin_amdgcn_sched_barrier(0);
            if (c >= 2 && lane == 0) *pf = c - 1;
        }
        VMWAIT(16);
        __builtin_amdgcn_sched_barrier(0);
        if (lane == 0) *pf = NCH - 1;
        VMWAIT(0);
        __builtin_amdgcn_sched_barrier(0);
        if (lane == 0) *pf = NCH;
    } else {
        // CONSUMER: zero VMEM; gather-ahead register double-buffer.
        volatile int* pf = &prodf;
        volatile int* cf = &consf;
        float plA[CH], pbA[CH], plB[CH], pbB[CH];

        POLL(1);
        GATHER_TO(plA, pbA, 0);
        // Activation pairs: chunks (0,1),(2,3),...,(8,9).
        for (int c = 0; c < 10; c += 2) {
            POLL(c + 2);
            GATHER_TO(plB, pbB, (c + 1) % NBUF);
            ACT_FROM(plA, pbA);                 // chunk c
            if (lane == 0) *cf = c + 1;
            POLL(c + 3);
            GATHER_TO(plA, pbA, (c + 2) % NBUF);
            ACT_FROM(plB, pbB);                 // chunk c+1
            if (lane == 0) *cf = c + 2;
        }
        // Steady-state pairs: chunks (10,11),...,(60,61).
        for (int c = 10; c < 62; c += 2) {
            POLL(c + 2);
            GATHER_TO(plB, pbB, (c + 1) % NBUF);
            STREAM_FROM(plA, pbA);              // chunk c
            if (lane == 0) *cf = c + 1;
            POLL(c + 3);
            GATHER_TO(plA, pbA, (c + 2) % NBUF);
            STREAM_FROM(plB, pbB);              // chunk c+1
            if (lane == 0) *cf = c + 2;
        }
        // Final pair: chunk 62 (full) + chunk 63 (15 steps).
        POLL(NCH);
        GATHER_TO(plB, pbB, (NCH - 1) % NBUF);
        STREAM_FROM(plA, pbA);                  // chunk 62
        if (lane == 0) *cf = NCH - 1;
        TAIL_FROM(plB, pbB);                    // chunk 63
        if (lane == 0) *cf = NCH;
    }

#undef TAIL_FROM
#undef STREAM_FROM
#undef ACT_FROM
#undef GATHER_TO
#undef POLL
#undef STREAM_STEP
#undef ACT_STEP
#undef ISSUE_CHUNK
#undef RESCALE

    // Terminal (consumer wave): states 2*len and 2*len-1 via uniform shuffles.
    if (wid == 0) {
        const int len = target_lengths[b];
        float la0 = flog2(a0) + (float)el;
        float la1 = flog2(a1) + (float)el;
        float la2 = flog2(a2) + (float)el;
        float x = (len == S_DIM) ? __shfl(la2, 63, 64) : __shfl(la0, len, 64);
        float y = __shfl(la1, len - 1, 64);
        if (lane == 0) {
            float mx = fmaxf(x, y);
            float lse2 = mx + flog2(1.0f + fexp2(-fabsf(x - y)));
            float loss = -(lse2 * LN2);
            if (!isfinite(loss) || !(loss < 1e29f)) loss = 0.0f;
            per_batch[b] = loss / (float)len;
        }
    }
}

// Single-wave deterministic reduction: mean over B of per_batch.
__global__ __launch_bounds__(64) void ctc_reduce_kernel(
    const float* __restrict__ per_batch, float* __restrict__ out)
{
    const int lane = threadIdx.x;
    float v = per_batch[lane] + per_batch[lane + 64];
    #pragma unroll
    for (int off = 32; off > 0; off >>= 1) {
        v += __shfl_down(v, off, 64);
    }
    if (lane == 0) out[0] = v / (float)B_DIM;
}

extern "C" void kernel_launch(void* const* d_in, const int* in_sizes, int n_in,
                              void* d_out, int out_size, void* d_ws, size_t ws_size,
                              hipStream_t stream) {
    const float* log_probs = (const float*)d_in[0];
    const int* targets = (const int*)d_in[1];
    const int* target_lengths = (const int*)d_in[2];
    float* out = (float*)d_out;
    float* per_batch = (float*)d_ws;  // B_DIM floats of scratch

    ctc_alpha_kernel<<<B_DIM, 128, 0, stream>>>(log_probs, targets,
                                                target_lengths, per_batch);
    ctc_reduce_kernel<<<1, 64, 0, stream>>>(per_batch, out);
}

// Round 18
// 45.830 us; speedup vs baseline: 1.5942x; 1.1295x over previous
//
#include <hip/hip_runtime.h>
#include <math.h>

#define LOG2E  1.4426950408889634f
#define LN2    0.6931471805599453f

// Problem constants (fixed by setup_inputs)
#define T_DIM 1024
#define B_DIM 128
#define C_DIM 256
#define S_DIM 64
#define L_DIM (2 * S_DIM + 1)  // 129
#define CH 16                  // timesteps per chunk
#define NCH (T_DIM / CH)       // 64 chunks
#define RBN 4                  // raw-row ring (64 KB)
#define PBN 6                  // converted-pair ring (48 KB)

__device__ __forceinline__ float fexp2(float x) { return __builtin_amdgcn_exp2f(x); }
__device__ __forceinline__ float flog2(float x) { return __builtin_amdgcn_logf(x); }

// lane i <- lane i-1; lane 0 <- 0. wave_shr:1 DPP (gfx9 ctrl 0x138).
__device__ __forceinline__ int dpp_shr1_i(int x) {
    return __builtin_amdgcn_update_dpp(0, x, 0x138 /*WAVE_SHR1*/, 0xF, 0xF, false);
}

// Async global->LDS, 16B per lane (per-lane src, wave-uniform dest).
#define GLOAD_LDS16(gp, lp)                                                    \
    __builtin_amdgcn_global_load_lds(                                          \
        (const __attribute__((address_space(1))) void*)(gp),                   \
        (__attribute__((address_space(3))) void*)(lp), 16, 0, 0)

#define VMWAIT(N_) asm volatile("s_waitcnt vmcnt(" #N_ ")" ::: "memory")
#define LGKM0()    asm volatile("s_waitcnt lgkmcnt(0)" ::: "memory")
#define FENCE()                                                                \
    do { __builtin_amdgcn_sched_barrier(0);                                    \
         asm volatile("" ::: "memory"); } while (0)

// 4-WAVE PIPELINE per block (one block per batch element):
//   w1 STAGER:     global_load_lds raw class rows -> rbuf ring, owns vmcnt,
//                  publishes sf = # chunks landed.
//   w2/w3 CONVERT: alternating chunks: divergent e1-gather from rbuf,
//                  exp2-convert, write packed float2{plv,pbv} -> pcv ring,
//                  publish cvE/cvO.
//   w0 CONSUMER:   poll -> 16 contiguous ds_read_b64 (gather-ahead register
//                  double-buffer) -> 16 exp-free recursion steps.
// Alpha: LINEAR domain, per-lane exponent el (true_alpha = a * 2^el).
__global__ __launch_bounds__(256) void ctc_alpha_kernel(
    const float* __restrict__ log_probs,    // (T, B, C)
    const int* __restrict__ targets,        // (B, S)
    const int* __restrict__ target_lengths, // (B,)
    float* __restrict__ per_batch)          // (B,) loss_b / len_b
{
    const int b = blockIdx.x;
    const int tid = threadIdx.x;
    const int lane = tid & 63;
    const int wid = tid >> 6;  // 0 consumer, 1 stager, 2 conv-even, 3 conv-odd

    __shared__ float  rbuf[RBN][CH][C_DIM];  // 64 KB raw class rows
    __shared__ float2 pcv[PBN][CH][64];      // 48 KB converted {plv,pbv}
    __shared__ int sf;     // # raw chunks landed
    __shared__ int cvE;    // # even chunks converted
    __shared__ int cvO;    // # odd chunks converted
    __shared__ int consf;  // # chunks consumed

    const int e1 = targets[b * S_DIM + lane];               // class of state 2l+1
    const int ep = (lane > 0) ? targets[b * S_DIM + lane - 1] : 0;
    const bool skip = (lane > 0) && (e1 != ep);

    const float* base = log_probs + (size_t)b * C_DIM;
    const size_t stride = (size_t)B_DIM * C_DIM;  // floats per timestep

    // t = 0 init (linear domain, scale el=0) — used by consumer.
    float i0 = base[0];
    float ie = base[e1];
    float a0 = (lane == 0) ? fexp2(i0 * LOG2E) : 0.0f;  // alpha[0]
    float a1 = (lane == 0) ? fexp2(ie * LOG2E) : 0.0f;  // alpha[1]
    float a2 = 0.0f;                                    // alpha[128]
    int el = 0;    // per-lane: log2(true alpha) = log2(a) + el
    int dexp = 0;  // eprev - el within a 4-step rescale window

    if (tid == 0) { sf = 0; cvE = 0; cvO = 0; consf = 0; }
    __syncthreads();  // the only barrier in the kernel

    volatile int* vsf = &sf;
    volatile int* vcE = &cvE;
    volatile int* vcO = &cvO;
    volatile int* vcf = &consf;

#define RESCALE()                                                              \
    do {                                                                       \
        float mx_ = fmaxf(a0, fmaxf(a1, a2));                                  \
        int eb_ = (int)((__float_as_uint(mx_) >> 23) & 0xFFu) - 127;           \
        el += eb_;                                                             \
        float sc_ = __uint_as_float((unsigned)(127 - eb_) << 23);              \
        a0 *= sc_; a1 *= sc_; a2 *= sc_;                                       \
    } while (0)

#define ISSUE_CHUNK(C_, BUF_)                                                  \
    do {                                                                       \
        const int t0_ = 1 + CH * (C_);                                         \
        _Pragma("unroll")                                                      \
        for (int k_ = 0; k_ < CH; ++k_) {                                      \
            int t_ = t0_ + k_;                                                 \
            t_ = (t_ < T_DIM) ? t_ : (T_DIM - 1);                              \
            GLOAD_LDS16(base + (size_t)t_ * stride + 4 * lane,                 \
                        &rbuf[BUF_][k_][0]);                                   \
        }                                                                      \
    } while (0)

    // Activation-phase step (chunks 0..9): full virgin-adopt logic.
    // PBV/PLV are pre-converted linear probabilities.
#define ACT_STEP(PBV, PLV, K_)                                                 \
    do {                                                                       \
        float am1_ = __int_as_float(dpp_shr1_i(__float_as_int(a1)));           \
        int eprev_ = dpp_shr1_i(el);                                           \
        int iz_ = __float_as_int(a0) | __float_as_int(a1) |                    \
                  __float_as_int(a2);                                          \
        int ele_ = (iz_ == 0) ? eprev_ : el;                                   \
        float am1s_ = ldexpf(am1_, eprev_ - ele_);                             \
        el = ele_;                                                             \
        float n0_ = (a0 + am1s_) * (PBV);                                      \
        float s2_ = skip ? am1s_ : 0.0f;                                       \
        float n1_ = (a1 + a0 + s2_) * (PLV);                                   \
        float n2_ = (a2 + a1) * (PBV);                                         \
        a0 = n0_; a1 = n1_; a2 = n2_;                                          \
        if (((K_) & 3) == 3) RESCALE();                                        \
    } while (0)

    // Steady-state step: dexp reused within the 4-step rescale window.
#define STREAM_STEP(PBV, PLV)                                                  \
    do {                                                                       \
        float am1_ = __int_as_float(dpp_shr1_i(__float_as_int(a1)));           \
        float am1s_ = ldexpf(am1_, dexp);                                      \
        float n0_ = (a0 + am1s_) * (PBV);                                      \
        float s2_ = skip ? am1s_ : 0.0f;                                       \
        float n1_ = (a1 + a0 + s2_) * (PLV);                                   \
        float n2_ = (a2 + a1) * (PBV);                                         \
        a0 = n0_; a1 = n1_; a2 = n2_;                                          \
    } while (0)

    // Consumer: chunk C_ ready?  even: cvE >= C_/2+1, odd: cvO >= (C_+1)/2.
#define POLLC(C_)                                                              \
    do {                                                                       \
        const int cc_ = (C_);                                                  \
        if (cc_ & 1) { while (*vcO < (cc_ + 1) / 2) { } }                      \
        else         { while (*vcE < cc_ / 2 + 1) { } }                        \
        FENCE();                                                               \
    } while (0)

    // Contiguous float2 gather into NAMED register sets (ds_read_b64).
#define GATHER_TO(PLX, PBX, SLOT)                                              \
    do {                                                                       \
        _Pragma("unroll")                                                      \
        for (int k_ = 0; k_ < CH; ++k_) {                                      \
            float2 v_ = pcv[SLOT][k_][lane];                                   \
            PLX[k_] = v_.x; PBX[k_] = v_.y;                                    \
        }                                                                      \
    } while (0)

#define ACT_FROM(PLX, PBX)                                                     \
    do {                                                                       \
        _Pragma("unroll")                                                      \
        for (int k_ = 0; k_ < CH; ++k_) {                                      \
            ACT_STEP(PBX[k_], PLX[k_], k_);                                    \
        }                                                                      \
    } while (0)

#define STREAM_FROM(PLX, PBX)                                                  \
    do {                                                                       \
        _Pragma("unroll")                                                      \
        for (int q_ = 0; q_ < 4; ++q_) {                                       \
            dexp = dpp_shr1_i(el) - el;                                        \
            STREAM_STEP(PBX[4 * q_ + 0], PLX[4 * q_ + 0]);                     \
            STREAM_STEP(PBX[4 * q_ + 1], PLX[4 * q_ + 1]);                     \
            STREAM_STEP(PBX[4 * q_ + 2], PLX[4 * q_ + 2]);                     \
            STREAM_STEP(PBX[4 * q_ + 3], PLX[4 * q_ + 3]);                     \
            RESCALE();                                                         \
        }                                                                      \
    } while (0)

#define TAIL_FROM(PLX, PBX)                                                    \
    do {                                                                       \
        _Pragma("unroll")                                                      \
        for (int q_ = 0; q_ < 3; ++q_) {                                       \
            dexp = dpp_shr1_i(el) - el;                                        \
            STREAM_STEP(PBX[4 * q_ + 0], PLX[4 * q_ + 0]);                     \
            STREAM_STEP(PBX[4 * q_ + 1], PLX[4 * q_ + 1]);                     \
            STREAM_STEP(PBX[4 * q_ + 2], PLX[4 * q_ + 2]);                     \
            STREAM_STEP(PBX[4 * q_ + 3], PLX[4 * q_ + 3]);                     \
            RESCALE();                                                         \
        }                                                                      \
        dexp = dpp_shr1_i(el) - el;                                            \
        STREAM_STEP(PBX[12], PLX[12]);                                         \
        STREAM_STEP(PBX[13], PLX[13]);                                         \
        STREAM_STEP(PBX[14], PLX[14]);                                         \
    } while (0)

    if (wid == 1) {
        // STAGER: free-running; only waits on raw-buffer reuse + vmcnt.
        for (int c = 0; c < NCH; ++c) {
            if (c >= RBN) {
                const int d = c - RBN;  // chunk previously in this slot
                if (d & 1) { while (*vcO < (d + 1) / 2) __builtin_amdgcn_s_sleep(1); }
                else       { while (*vcE < d / 2 + 1) __builtin_amdgcn_s_sleep(1); }
                FENCE();
            }
            ISSUE_CHUNK(c, c & (RBN - 1));
            VMWAIT(32);  // chunks <= c-2 have fully landed
            FENCE();
            if (c >= 2 && lane == 0) *vsf = c - 1;
        }
        VMWAIT(16);
        FENCE();
        if (lane == 0) *vsf = NCH - 1;
        VMWAIT(0);
        FENCE();
        if (lane == 0) *vsf = NCH;
    } else if (wid >= 2) {
        // CONVERTER (par 0 = even chunks, par 1 = odd chunks).
        const int par = wid - 2;
        for (int c = par; c < NCH; c += 2) {
            while (*vsf < c + 1) { }          // raw chunk c landed?
            if (c >= PBN) {                    // pcv slot free?
                while (*vcf < c - PBN + 1) __builtin_amdgcn_s_sleep(1);
            }
            FENCE();
            const int rb = c & (RBN - 1);
            const int pb = c % PBN;
            #pragma unroll
            for (int k_ = 0; k_ < CH; ++k_) {
                float pl_ = rbuf[rb][k_][e1];
                float pb_ = rbuf[rb][k_][0];
                float2 v_;
                v_.x = fexp2(pl_ * LOG2E);
                v_.y = fexp2(pb_ * LOG2E);
                pcv[pb][k_][lane] = v_;
            }
            LGKM0();  // pair writes visible before flag
            if (lane == 0) {
                if (par) *vcO = (c + 1) / 2;
                else     *vcE = c / 2 + 1;
            }
        }
    } else {
        // CONSUMER: zero VMEM, zero transcendentals, gather-ahead dbuf.
        float plA[CH], pbA[CH], plB[CH], pbB[CH];

        POLLC(0);
        GATHER_TO(plA, pbA, 0);
        // Activation pairs: chunks (0,1),(2,3),...,(8,9).
        for (int c = 0; c < 10; c += 2) {
            POLLC(c + 1);
            GATHER_TO(plB, pbB, (c + 1) % PBN);
            ACT_FROM(plA, pbA);                 // chunk c
            if (lane == 0) *vcf = c + 1;
            POLLC(c + 2);
            GATHER_TO(plA, pbA, (c + 2) % PBN);
            ACT_FROM(plB, pbB);                 // chunk c+1
            if (lane == 0) *vcf = c + 2;
        }
        // Steady-state pairs: chunks (10,11),...,(60,61).
        for (int c = 10; c < 62; c += 2) {
            POLLC(c + 1);
            GATHER_TO(plB, pbB, (c + 1) % PBN);
            STREAM_FROM(plA, pbA);              // chunk c
            if (lane == 0) *vcf = c + 1;
            POLLC(c + 2);
            GATHER_TO(plA, pbA, (c + 2) % PBN);
            STREAM_FROM(plB, pbB);              // chunk c+1
            if (lane == 0) *vcf = c + 2;
        }
        // Final pair: chunk 62 (full) + chunk 63 (15 steps).
        POLLC(NCH - 1);
        GATHER_TO(plB, pbB, (NCH - 1) % PBN);
        STREAM_FROM(plA, pbA);                  // chunk 62
        if (lane == 0) *vcf = NCH - 1;
        TAIL_FROM(plB, pbB);                    // chunk 63
        if (lane == 0) *vcf = NCH;
    }

#undef TAIL_FROM
#undef STREAM_FROM
#undef ACT_FROM
#undef GATHER_TO
#undef POLLC
#undef STREAM_STEP
#undef ACT_STEP
#undef ISSUE_CHUNK
#undef RESCALE

    // Terminal (consumer wave): states 2*len and 2*len-1 via uniform shuffles.
    if (wid == 0) {
        const int len = target_lengths[b];
        float la0 = flog2(a0) + (float)el;
        float la1 = flog2(a1) + (float)el;
        float la2 = flog2(a2) + (float)el;
        float x = (len == S_DIM) ? __shfl(la2, 63, 64) : __shfl(la0, len, 64);
        float y = __shfl(la1, len - 1, 64);
        if (lane == 0) {
            float mx = fmaxf(x, y);
            float lse2 = mx + flog2(1.0f + fexp2(-fabsf(x - y)));
            float loss = -(lse2 * LN2);
            if (!isfinite(loss) || !(loss < 1e29f)) loss = 0.0f;
            per_batch[b] = loss / (float)len;
        }
    }
}

// Single-wave deterministic reduction: mean over B of per_batch.
__global__ __launch_bounds__(64) void ctc_reduce_kernel(
    const float* __restrict__ per_batch, float* __restrict__ out)
{
    const int lane = threadIdx.x;
    float v = per_batch[lane] + per_batch[lane + 64];
    #pragma unroll
    for (int off = 32; off > 0; off >>= 1) {
        v += __shfl_down(v, off, 64);
    }
    if (lane == 0) out[0] = v / (float)B_DIM;
}

extern "C" void kernel_launch(void* const* d_in, const int* in_sizes, int n_in,
                              void* d_out, int out_size, void* d_ws, size_t ws_size,
                              hipStream_t stream) {
    const float* log_probs = (const float*)d_in[0];
    const int* targets = (const int*)d_in[1];
    const int* target_lengths = (const int*)d_in[2];
    float* out = (float*)d_out;
    float* per_batch = (float*)d_ws;  // B_DIM floats of scratch

    ctc_alpha_kernel<<<B_DIM, 256, 0, stream>>>(log_probs, targets,
                                                target_lengths, per_batch);
    ctc_reduce_kernel<<<1, 64, 0, stream>>>(per_batch, out);
}

// Round 19
// 45.379 us; speedup vs baseline: 1.6101x; 1.0099x over previous
//
#include <hip/hip_runtime.h>
#include <math.h>

#define LOG2E  1.4426950408889634f
#define LN2    0.6931471805599453f

// Problem constants (fixed by setup_inputs)
#define T_DIM 1024
#define B_DIM 128
#define C_DIM 256
#define S_DIM 64
#define CH 16                   // timesteps per chunk
#define NCHD 32                 // chunks per direction (511 steps each)
#define RBN 3                   // raw-row ring per direction (48 KB)
#define PBN 3                   // converted-pair ring per direction (24 KB)

__device__ __forceinline__ float fexp2(float x) { return __builtin_amdgcn_exp2f(x); }
__device__ __forceinline__ float flog2(float x) { return __builtin_amdgcn_logf(x); }

// lane i <- lane i-1 (shr) / lane i+1 (shl); vacated lanes <- 0.
__device__ __forceinline__ int dpp_shr1_i(int x) {
    return __builtin_amdgcn_update_dpp(0, x, 0x138, 0xF, 0xF, false);
}
__device__ __forceinline__ int dpp_shl1_i(int x) {
    return __builtin_amdgcn_update_dpp(0, x, 0x130, 0xF, 0xF, false);
}
// Canonical wave64 reductions (result lands in lane 63).
template <int C> __device__ __forceinline__ float dpp_maxf(float m) {
    int s = __builtin_amdgcn_update_dpp(__float_as_int(m), __float_as_int(m),
                                        C, 0xF, 0xF, false);
    return fmaxf(m, __int_as_float(s));
}
template <int C> __device__ __forceinline__ float dpp_addf(float v) {
    int s = __builtin_amdgcn_update_dpp(0, __float_as_int(v), C, 0xF, 0xF, false);
    return v + __int_as_float(s);
}

#define GLOAD_LDS16(gp, lp)                                                    \
    __builtin_amdgcn_global_load_lds(                                          \
        (const __attribute__((address_space(1))) void*)(gp),                   \
        (__attribute__((address_space(3))) void*)(lp), 16, 0, 0)

#define VMWAIT(N_) asm volatile("s_waitcnt vmcnt(" #N_ ")" ::: "memory")
#define LGKM0()    asm volatile("s_waitcnt lgkmcnt(0)" ::: "memory")
#define FENCE()                                                                \
    do { __builtin_amdgcn_sched_barrier(0);                                    \
         asm volatile("" ::: "memory"); } while (0)

// BIDIRECTIONAL 8-WAVE PIPELINE (one block = one batch element, 512 thr):
//   waves 1/5: stagers (fwd/bwd) — global_load_lds raw rows, own vmcnt.
//   waves 2,3 / 6,7: converters — e1-gather + exp2 -> packed float2 ring.
//   wave 0: forward alpha consumer (t=1..511), wave 4: backward beta
//   consumer (t=1022..512). Meet: P = sum_s alpha_511[s]*gamma[s],
//   gamma[s] = beta_512[s]+beta_512[s+1]+skip(s)*beta_512[s+2].
// Alpha/beta: LINEAR domain, per-lane exponent (true = v * 2^el).
__global__ __launch_bounds__(512) void ctc_alpha_kernel(
    const float* __restrict__ log_probs,    // (T, B, C)
    const int* __restrict__ targets,        // (B, S)
    const int* __restrict__ target_lengths, // (B,)
    float* __restrict__ per_batch)          // (B,) loss_b / len_b
{
    const int b = blockIdx.x;
    const int tid = threadIdx.x;
    const int lane = tid & 63;
    const int wid = tid >> 6;

    __shared__ float  rbF[RBN][CH][C_DIM];  // 48 KB fwd raw rows
    __shared__ float  rbB[RBN][CH][C_DIM];  // 48 KB bwd raw rows
    __shared__ float2 pcF[PBN][CH][64];     // 24 KB fwd {plv,pbv}
    __shared__ float2 pcB[PBN][CH][64];     // 24 KB bwd {plv,pbv}
    __shared__ float gam0[64], gam1[64];    // gamma handoff
    __shared__ int   gelB[64];
    __shared__ float gam2s;
    __shared__ int sfF, cvEF, cvOF, cfF, sfB, cvEB, cvOB, cfB;

    const int e1 = targets[b * S_DIM + lane];
    const int ep = (lane > 0) ? targets[b * S_DIM + lane - 1] : 0;
    const bool skipf = (lane > 0) && (e1 != ep);   // fwd: s-2 -> s (s=2l+1)
    const int en = dpp_shl1_i(e1);                 // next lane's label
    const bool skipb = (lane < 63) && (en != e1);  // bwd: s -> s+2 (s=2l+1)
    const bool is63 = (lane == 63);
    const int len = target_lengths[b];

    const float* base = log_probs + (size_t)b * C_DIM;
    const size_t stride = (size_t)B_DIM * C_DIM;

    if (tid == 0) {
        sfF = 0; cvEF = 0; cvOF = 0; cfF = 0;
        sfB = 0; cvEB = 0; cvOB = 0; cfB = 0;
    }
    __syncthreads();

    volatile int* vsfF = &sfF; volatile int* vcEF = &cvEF;
    volatile int* vcOF = &cvOF; volatile int* vcfF = &cfF;
    volatile int* vsfB = &sfB; volatile int* vcEB = &cvEB;
    volatile int* vcOB = &cvOB; volatile int* vcfB = &cfB;

#define STAGER_BODY(RB_, VSF_, VCE_, VCO_, T0_, SGN_)                          \
    do {                                                                       \
        for (int c = 0; c < NCHD; ++c) {                                       \
            if (c >= RBN) {                                                    \
                const int d_ = c - RBN;                                        \
                if (d_ & 1) { while (*VCO_ < (d_ + 1) / 2) __builtin_amdgcn_s_sleep(1); } \
                else        { while (*VCE_ < d_ / 2 + 1) __builtin_amdgcn_s_sleep(1); }  \
                FENCE();                                                       \
            }                                                                  \
            const int rb_ = c % RBN;                                           \
            _Pragma("unroll")                                                  \
            for (int k_ = 0; k_ < CH; ++k_) {                                  \
                const int t_ = (T0_) + (SGN_) * (16 * c + k_);                 \
                GLOAD_LDS16(base + (size_t)t_ * stride + 4 * lane,             \
                            &RB_[rb_][k_][0]);                                 \
            }                                                                  \
            VMWAIT(32);                                                        \
            FENCE();                                                           \
            if (c >= 2 && lane == 0) *VSF_ = c - 1;                            \
        }                                                                      \
        VMWAIT(16); FENCE(); if (lane == 0) *VSF_ = NCHD - 1;                  \
        VMWAIT(0);  FENCE(); if (lane == 0) *VSF_ = NCHD;                      \
    } while (0)

#define CONV_BODY(RB_, PC_, VSF_, VMYF_, VCF_, PAR_)                           \
    do {                                                                       \
        for (int c = PAR_; c < NCHD; c += 2) {                                 \
            while (*VSF_ < c + 1) { }                                          \
            if (c >= PBN) {                                                    \
                while (*VCF_ < c - PBN + 1) __builtin_amdgcn_s_sleep(1);       \
            }                                                                  \
            FENCE();                                                           \
            const int rb_ = c % RBN;                                           \
            const int pb_ = c % PBN;                                           \
            _Pragma("unroll")                                                  \
            for (int k_ = 0; k_ < CH; ++k_) {                                  \
                float pl_ = RB_[rb_][k_][e1];                                  \
                float pbl_ = RB_[rb_][k_][0];                                  \
                float2 v_;                                                     \
                v_.x = fexp2(pl_ * LOG2E);                                     \
                v_.y = fexp2(pbl_ * LOG2E);                                    \
                PC_[pb_][k_][lane] = v_;                                       \
            }                                                                  \
            LGKM0();                                                           \
            if (lane == 0) *VMYF_ = (PAR_) ? (c + 1) / 2 : c / 2 + 1;          \
        }                                                                      \
    } while (0)

#define POLLG(VCE_, VCO_, C_)                                                  \
    do { const int cc_ = (C_);                                                 \
         if (cc_ & 1) { while (*VCO_ < (cc_ + 1) / 2) { } }                    \
         else         { while (*VCE_ < cc_ / 2 + 1) { } }                      \
         FENCE(); } while (0)

#define GATHER_G(PC_, PLX, PBX, SLOT)                                          \
    do { _Pragma("unroll")                                                     \
         for (int k_ = 0; k_ < CH; ++k_) {                                     \
             float2 v_ = PC_[SLOT][k_][lane];                                  \
             PLX[k_] = v_.x; PBX[k_] = v_.y;                                   \
         } } while (0)

    if (wid == 1) {
        STAGER_BODY(rbF, vsfF, vcEF, vcOF, 1, 1);
    } else if (wid == 5) {
        STAGER_BODY(rbB, vsfB, vcEB, vcOB, 1022, -1);
    } else if (wid == 2) {
        CONV_BODY(rbF, pcF, vsfF, vcEF, vcfF, 0);
    } else if (wid == 3) {
        CONV_BODY(rbF, pcF, vsfF, vcOF, vcfF, 1);
    } else if (wid == 6) {
        CONV_BODY(rbB, pcB, vsfB, vcEB, vcfB, 0);
    } else if (wid == 7) {
        CONV_BODY(rbB, pcB, vsfB, vcOB, vcfB, 1);
    } else if (wid == 0) {
        // ===== FORWARD alpha consumer: t = 1..511 =====
        float a0, a1, a2; int el = 0, dexp = 0;
        {
            float i0 = base[0], ie = base[e1];
            a0 = (lane == 0) ? fexp2(i0 * LOG2E) : 0.0f;
            a1 = (lane == 0) ? fexp2(ie * LOG2E) : 0.0f;
            a2 = 0.0f;
        }
#define RESCALE_F()                                                            \
    do { float mx_ = fmaxf(a0, fmaxf(a1, a2));                                 \
         int eb_ = (int)((__float_as_uint(mx_) >> 23) & 0xFFu) - 127;          \
         el += eb_;                                                            \
         float sc_ = __uint_as_float((unsigned)(127 - eb_) << 23);             \
         a0 *= sc_; a1 *= sc_; a2 *= sc_; } while (0)
#define ACT_STEP_F(PBV, PLV, K_)                                               \
    do { float am1_ = __int_as_float(dpp_shr1_i(__float_as_int(a1)));          \
         int eprev_ = dpp_shr1_i(el);                                          \
         int iz_ = __float_as_int(a0) | __float_as_int(a1) |                   \
                   __float_as_int(a2);                                         \
         int ele_ = (iz_ == 0) ? eprev_ : el;                                  \
         float am1s_ = ldexpf(am1_, eprev_ - ele_);                            \
         el = ele_;                                                            \
         float n0_ = (a0 + am1s_) * (PBV);                                     \
         float s2_ = skipf ? am1s_ : 0.0f;                                     \
         float n1_ = (a1 + a0 + s2_) * (PLV);                                  \
         float n2_ = (a2 + a1) * (PBV);                                        \
         a0 = n0_; a1 = n1_; a2 = n2_;                                         \
         if (((K_) & 3) == 3) RESCALE_F(); } while (0)
#define STREAM_STEP_F(PBV, PLV)                                                \
    do { float am1_ = __int_as_float(dpp_shr1_i(__float_as_int(a1)));          \
         float am1s_ = ldexpf(am1_, dexp);                                     \
         float n0_ = (a0 + am1s_) * (PBV);                                     \
         float s2_ = skipf ? am1s_ : 0.0f;                                     \
         float n1_ = (a1 + a0 + s2_) * (PLV);                                  \
         float n2_ = (a2 + a1) * (PBV);                                        \
         a0 = n0_; a1 = n1_; a2 = n2_; } while (0)
#define ACT_FROM_F(PLX, PBX)                                                   \
    do { _Pragma("unroll")                                                     \
         for (int k_ = 0; k_ < CH; ++k_) ACT_STEP_F(PBX[k_], PLX[k_], k_);     \
    } while (0)
#define STREAM_FROM_F(PLX, PBX)                                                \
    do { _Pragma("unroll")                                                     \
         for (int q_ = 0; q_ < 4; ++q_) {                                      \
             dexp = dpp_shr1_i(el) - el;                                       \
             STREAM_STEP_F(PBX[4 * q_ + 0], PLX[4 * q_ + 0]);                  \
             STREAM_STEP_F(PBX[4 * q_ + 1], PLX[4 * q_ + 1]);                  \
             STREAM_STEP_F(PBX[4 * q_ + 2], PLX[4 * q_ + 2]);                  \
             STREAM_STEP_F(PBX[4 * q_ + 3], PLX[4 * q_ + 3]);                  \
             RESCALE_F(); } } while (0)
#define TAIL_FROM_F(PLX, PBX)                                                  \
    do { _Pragma("unroll")                                                     \
         for (int q_ = 0; q_ < 3; ++q_) {                                      \
             dexp = dpp_shr1_i(el) - el;                                       \
             STREAM_STEP_F(PBX[4 * q_ + 0], PLX[4 * q_ + 0]);                  \
             STREAM_STEP_F(PBX[4 * q_ + 1], PLX[4 * q_ + 1]);                  \
             STREAM_STEP_F(PBX[4 * q_ + 2], PLX[4 * q_ + 2]);                  \
             STREAM_STEP_F(PBX[4 * q_ + 3], PLX[4 * q_ + 3]);                  \
             RESCALE_F(); }                                                    \
         dexp = dpp_shr1_i(el) - el;                                           \
         STREAM_STEP_F(PBX[12], PLX[12]);                                      \
         STREAM_STEP_F(PBX[13], PLX[13]);                                      \
         STREAM_STEP_F(PBX[14], PLX[14]); } while (0)

        float plA[CH], pbA[CH], plB[CH], pbB[CH];
        POLLG(vcEF, vcOF, 0);
        GATHER_G(pcF, plA, pbA, 0);
        for (int c = 0; c < 10; c += 2) {
            POLLG(vcEF, vcOF, c + 1);
            GATHER_G(pcF, plB, pbB, (c + 1) % PBN);
            ACT_FROM_F(plA, pbA);
            if (lane == 0) *vcfF = c + 1;
            POLLG(vcEF, vcOF, c + 2);
            GATHER_G(pcF, plA, pbA, (c + 2) % PBN);
            ACT_FROM_F(plB, pbB);
            if (lane == 0) *vcfF = c + 2;
        }
        for (int c = 10; c < 30; c += 2) {
            POLLG(vcEF, vcOF, c + 1);
            GATHER_G(pcF, plB, pbB, (c + 1) % PBN);
            STREAM_FROM_F(plA, pbA);
            if (lane == 0) *vcfF = c + 1;
            POLLG(vcEF, vcOF, c + 2);
            GATHER_G(pcF, plA, pbA, (c + 2) % PBN);
            STREAM_FROM_F(plB, pbB);
            if (lane == 0) *vcfF = c + 2;
        }
        POLLG(vcEF, vcOF, NCHD - 1);
        GATHER_G(pcF, plB, pbB, (NCHD - 1) % PBN);
        STREAM_FROM_F(plA, pbA);                 // chunk 30
        if (lane == 0) *vcfF = NCHD - 1;
        TAIL_FROM_F(plB, pbB);                   // chunk 31 (15 steps)
        if (lane == 0) *vcfF = NCHD;

        __syncthreads();  // beta side has published gamma

        // Combine: P = sum_s alpha_511[s] * gamma[s], in log2 domain.
        float la0 = flog2(a0) + (float)el;
        float la1 = flog2(a1) + (float)el;
        float g0 = gam0[lane], g1 = gam1[lane];
        float eB = (float)gelB[lane];
        float q0 = la0 + flog2(g0) + eB;
        float q1 = la1 + flog2(g1) + eB;
        float q2 = is63 ? (flog2(a2) + (float)el + flog2(gam2s) + eB) : -1e30f;
        q0 = fmaxf(q0, -1e30f); q1 = fmaxf(q1, -1e30f); q2 = fmaxf(q2, -1e30f);
        float ml = fmaxf(q0, fmaxf(q1, q2));
        float lw = ml + flog2(fexp2(q0 - ml) + fexp2(q1 - ml) + fexp2(q2 - ml));
        // wave LSE
        float m_ = lw;
        m_ = dpp_maxf<0x111>(m_); m_ = dpp_maxf<0x112>(m_);
        m_ = dpp_maxf<0x114>(m_); m_ = dpp_maxf<0x118>(m_);
        m_ = dpp_maxf<0x142>(m_); m_ = dpp_maxf<0x143>(m_);
        float M = __int_as_float(__builtin_amdgcn_readlane(__float_as_int(m_), 63));
        float v_ = fexp2(lw - M);
        v_ = dpp_addf<0x111>(v_); v_ = dpp_addf<0x112>(v_);
        v_ = dpp_addf<0x114>(v_); v_ = dpp_addf<0x118>(v_);
        v_ = dpp_addf<0x142>(v_); v_ = dpp_addf<0x143>(v_);
        float S = __int_as_float(__builtin_amdgcn_readlane(__float_as_int(v_), 63));
        if (lane == 0) {
            float lse2 = M + flog2(S);
            float loss = -(lse2 * LN2);
            if (!isfinite(loss) || !(loss < 1e29f)) loss = 0.0f;
            per_batch[b] = loss / (float)len;
        }
    } else {
        // ===== BACKWARD beta consumer (wid == 4): t = 1022..512 =====
        float b0, b1, b2; int elB = 0, dexB = 0, dex0 = 0;
        {
            const float* rowT = base + (size_t)(T_DIM - 1) * stride;
            float lpb_ = rowT[0], lpl_ = rowT[e1];
            b1 = (lane == len - 1) ? fexp2(lpl_ * LOG2E) : 0.0f;
            b0 = (lane == len && len < S_DIM) ? fexp2(lpb_ * LOG2E) : 0.0f;
            b2 = (len == S_DIM && is63) ? fexp2(lpb_ * LOG2E) : 0.0f;
        }
#define RESCALE_B()                                                            \
    do { float mx_ = fmaxf(b0, fmaxf(b1, b2));                                 \
         int eb_ = (int)((__float_as_uint(mx_) >> 23) & 0xFFu) - 127;          \
         elB += eb_;                                                           \
         float sc_ = __uint_as_float((unsigned)(127 - eb_) << 23);             \
         b0 *= sc_; b1 *= sc_; b2 *= sc_; } while (0)
#define ACT_STEP_B(PBV, PLV, K_)                                               \
    do { float nb0_ = __int_as_float(dpp_shl1_i(__float_as_int(b0)));          \
         nb0_ = is63 ? b2 : nb0_;                                              \
         float nb1_ = __int_as_float(dpp_shl1_i(__float_as_int(b1)));          \
         int en_ = dpp_shl1_i(elB);                                            \
         int iz_ = __float_as_int(b0) | __float_as_int(b1) |                   \
                   __float_as_int(b2);                                         \
         int eln_ = (iz_ == 0) ? en_ : elB;                                    \
         int d0_ = is63 ? (elB - eln_) : (en_ - eln_);                         \
         float nb0a_ = ldexpf(nb0_, d0_);                                      \
         float nb1a_ = ldexpf(nb1_, en_ - eln_);                               \
         elB = eln_;                                                           \
         float n0_ = (b0 + b1) * (PBV);                                        \
         float n1_ = (b1 + nb0a_ + (skipb ? nb1a_ : 0.0f)) * (PLV);            \
         float n2_ = b2 * (PBV);                                               \
         b0 = n0_; b1 = n1_; b2 = n2_;                                         \
         if (((K_) & 3) == 3) RESCALE_B(); } while (0)
#define STREAM_STEP_B(PBV, PLV)                                                \
    do { float nb0_ = __int_as_float(dpp_shl1_i(__float_as_int(b0)));          \
         nb0_ = is63 ? b2 : nb0_;                                              \
         float nb1_ = __int_as_float(dpp_shl1_i(__float_as_int(b1)));          \
         float nb0a_ = ldexpf(nb0_, dex0);                                     \
         float nb1a_ = ldexpf(nb1_, dexB);                                     \
         float n0_ = (b0 + b1) * (PBV);                                        \
         float n1_ = (b1 + nb0a_ + (skipb ? nb1a_ : 0.0f)) * (PLV);            \
         float n2_ = b2 * (PBV);                                               \
         b0 = n0_; b1 = n1_; b2 = n2_; } while (0)
#define SET_DEX_B()                                                            \
    do { dexB = dpp_shl1_i(elB) - elB; dex0 = is63 ? 0 : dexB; } while (0)
#define ACT_FROM_B(PLX, PBX)                                                   \
    do { _Pragma("unroll")                                                     \
         for (int k_ = 0; k_ < CH; ++k_) ACT_STEP_B(PBX[k_], PLX[k_], k_);     \
    } while (0)
#define STREAM_FROM_B(PLX, PBX)                                                \
    do { _Pragma("unroll")                                                     \
         for (int q_ = 0; q_ < 4; ++q_) {                                      \
             SET_DEX_B();                                                      \
             STREAM_STEP_B(PBX[4 * q_ + 0], PLX[4 * q_ + 0]);                  \
             STREAM_STEP_B(PBX[4 * q_ + 1], PLX[4 * q_ + 1]);                  \
             STREAM_STEP_B(PBX[4 * q_ + 2], PLX[4 * q_ + 2]);                  \
             STREAM_STEP_B(PBX[4 * q_ + 3], PLX[4 * q_ + 3]);                  \
             RESCALE_B(); } } while (0)
#define TAIL_FROM_B(PLX, PBX)                                                  \
    do { _Pragma("unroll")                                                     \
         for (int q_ = 0; q_ < 3; ++q_) {                                      \
             SET_DEX_B();                                                      \
             STREAM_STEP_B(PBX[4 * q_ + 0], PLX[4 * q_ + 0]);                  \
             STREAM_STEP_B(PBX[4 * q_ + 1], PLX[4 * q_ + 1]);                  \
             STREAM_STEP_B(PBX[4 * q_ + 2], PLX[4 * q_ + 2]);                  \
             STREAM_STEP_B(PBX[4 * q_ + 3], PLX[4 * q_ + 3]);                  \
             RESCALE_B(); }                                                    \
         SET_DEX_B();                                                          \
         STREAM_STEP_B(PBX[12], PLX[12]);                                      \
         STREAM_STEP_B(PBX[13], PLX[13]);                                      \
         STREAM_STEP_B(PBX[14], PLX[14]); } while (0)

        float plA[CH], pbA[CH], plB[CH], pbB[CH];
        POLLG(vcEB, vcOB, 0);
        GATHER_G(pcB, plA, pbA, 0);
        for (int c = 0; c < 10; c += 2) {
            POLLG(vcEB, vcOB, c + 1);
            GATHER_G(pcB, plB, pbB, (c + 1) % PBN);
            ACT_FROM_B(plA, pbA);
            if (lane == 0) *vcfB = c + 1;
            POLLG(vcEB, vcOB, c + 2);
            GATHER_G(pcB, plA, pbA, (c + 2) % PBN);
            ACT_FROM_B(plB, pbB);
            if (lane == 0) *vcfB = c + 2;
        }
        for (int c = 10; c < 30; c += 2) {
            POLLG(vcEB, vcOB, c + 1);
            GATHER_G(pcB, plB, pbB, (c + 1) % PBN);
            STREAM_FROM_B(plA, pbA);
            if (lane == 0) *vcfB = c + 1;
            POLLG(vcEB, vcOB, c + 2);
            GATHER_G(pcB, plA, pbA, (c + 2) % PBN);
            STREAM_FROM_B(plB, pbB);
            if (lane == 0) *vcfB = c + 2;
        }
        POLLG(vcEB, vcOB, NCHD - 1);
        GATHER_G(pcB, plB, pbB, (NCHD - 1) % PBN);
        STREAM_FROM_B(plA, pbA);                 // chunk 30
        if (lane == 0) *vcfB = NCHD - 1;
        TAIL_FROM_B(plB, pbB);                   // chunk 31 (15 steps)
        if (lane == 0) *vcfB = NCHD;

        // gamma[s] from beta_512 (exponent-aligned), publish for wave 0.
        {
            float nb0_ = __int_as_float(dpp_shl1_i(__float_as_int(b0)));
            nb0_ = is63 ? b2 : nb0_;
            float nb1_ = __int_as_float(dpp_shl1_i(__float_as_int(b1)));
            int en_ = dpp_shl1_i(elB);
            int d_ = is63 ? 0 : (en_ - elB);
            float nb0a_ = ldexpf(nb0_, d_);
            float nb1a_ = ldexpf(nb1_, d_);
            gam0[lane] = b0 + b1;
            gam1[lane] = b1 + nb0a_ + (skipb ? nb1a_ : 0.0f);
            gelB[lane] = elB;
            if (is63) gam2s = b2;
        }
        __syncthreads();
    }

    // stager/converter waves also hit the final barrier exactly once.
    if (wid != 0 && wid != 4) __syncthreads();
}

// Single-wave deterministic reduction: mean over B of per_batch.
__global__ __launch_bounds__(64) void ctc_reduce_kernel(
    const float* __restrict__ per_batch, float* __restrict__ out)
{
    const int lane = threadIdx.x;
    float v = per_batch[lane] + per_batch[lane + 64];
    #pragma unroll
    for (int off = 32; off > 0; off >>= 1) {
        v += __shfl_down(v, off, 64);
    }
    if (lane == 0) out[0] = v / (float)B_DIM;
}

extern "C" void kernel_launch(void* const* d_in, const int* in_sizes, int n_in,
                              void* d_out, int out_size, void* d_ws, size_t ws_size,
                              hipStream_t stream) {
    const float* log_probs = (const float*)d_in[0];
    const int* targets = (const int*)d_in[1];
    const int* target_lengths = (const int*)d_in[2];
    float* out = (float*)d_out;
    float* per_batch = (float*)d_ws;  // B_DIM floats of scratch

    ctc_alpha_kernel<<<B_DIM, 512, 0, stream>>>(log_probs, targets,
                                                target_lengths, per_batch);
    ctc_reduce_kernel<<<1, 64, 0, stream>>>(per_batch, out);
}